// Round 6
// baseline (488.253 us; speedup 1.0000x reference)
//
#include <hip/hip_runtime.h>
#include <hip/hip_bf16.h>

#define NPTS 131072
// transposed feature region offsets (elements, fp32) in ws feature area:
//   scale0: 56*56*64 = 200704, scale1: 28*28*128 = 100352,
//   scale2: 14*14*256 = 50176, scale3: 7*7*512 = 25088  -> total 376320
#define FT_TOTAL 376320

// native clang vector type — required by __builtin_nontemporal_store
typedef float f32x4 __attribute__((ext_vector_type(4)));

// ------------------------------------------------------------------
// Kernel 1: transpose feat[b] slices [C,H,W] -> [H*W, C] (fp32) so the
// per-point channel gather becomes contiguous (float4-vectorizable).
// Only 1.5 MB total — latency-trivial.
// ------------------------------------------------------------------
__global__ __launch_bounds__(256) void k_transpose(
    const float* __restrict__ f0,
    const float* __restrict__ f1,
    const float* __restrict__ f2,
    const float* __restrict__ f3,
    const int* __restrict__ batch,
    float* __restrict__ ft)
{
    int d = blockIdx.x * 256 + threadIdx.x;
    if (d >= FT_TOTAL) return;
    int b = *batch;
    const float* src;
    int local, c, p, hw;
    if (d < 200704) {
        local = d;          c = local & 63;  p = local >> 6; hw = 3136;
        src = f0 + (size_t)b * 64 * 3136;
    } else if (d < 301056) {
        local = d - 200704; c = local & 127; p = local >> 7; hw = 784;
        src = f1 + (size_t)b * 128 * 784;
    } else if (d < 351232) {
        local = d - 301056; c = local & 255; p = local >> 8; hw = 196;
        src = f2 + (size_t)b * 256 * 196;
    } else {
        local = d - 351232; c = local & 511; p = local >> 9; hw = 49;
        src = f3 + (size_t)b * 512 * 49;
    }
    ft[d] = src[c * hw + p];
}

// ------------------------------------------------------------------
// Kernel 2: fused projection + gather + write. ONE WAVE PER POINT:
// all 64 lanes redundantly compute the point's projection (broadcast
// pts loads, numerics identical to the verified round-2/4 code:
// __fdiv_rn/__fmul_rn/__fadd_rn, absmax==0.0), then each lane writes
// 4 float4 chunks (j = 64k + lane) -> per-instruction stores are
// fully-populated contiguous 1 KiB. Non-temporal stores keep the
// 504 MB stream out of L2. Invalid points skip all loads entirely.
// ------------------------------------------------------------------
__global__ __launch_bounds__(256) void k_gather(
    const float* __restrict__ pts,   // [N,3]
    const float* __restrict__ ft,    // transposed feats (L2-resident)
    float* __restrict__ out)         // [N, 960]
{
    int n = (blockIdx.x * 256 + threadIdx.x) >> 6;   // wave index = point
    int lane = threadIdx.x & 63;

    // --- projection (verified-exact numerics) ---
    float px = pts[3 * n + 0];
    float py = pts[3 * n + 1];
    float pz = pts[3 * n + 2];
    float qh = __fdiv_rn(py, pz);
    float qw = __fdiv_rn(px, -pz);
    float h = __fadd_rn(__fmul_rn(248.0f, qh), 111.5f);
    float w = __fadd_rn(__fmul_rn(248.0f, qw), 111.5f);
    h = fminf(fmaxf(h, 0.0f), 223.0f);
    w = fminf(fmaxf(w, 0.0f), 223.0f);

    const float scl[4] = {0.25f, 0.125f, 0.0625f, 0.03125f}; // S/224, exact pow2
    const int   S[4]   = {56, 28, 14, 7};
    int r[4];
#pragma unroll
    for (int s = 0; s < 4; ++s) {
        float x = h * scl[s];
        float y = w * scl[s];
        int x1 = (int)floorf(x);
        int x2 = min((int)ceilf(x), S[s] - 1);
        int y1 = (int)floorf(y);
        int y2 = min((int)ceilf(y), S[s] - 1);
        int bit = (x2 - x1) * (y2 - y1);   // 0 or 1
        r[s] = bit ? (x1 * S[s] + y1) : -1;
    }

    // --- gather + write: 4 chunks per lane ---
    float* rowout = out + (size_t)n * 960;
#pragma unroll
    for (int k = 0; k < 4; ++k) {
        int j = 64 * k + lane;          // float4-chunk index (0..239)
        if (j < 240) {                  // only k==3 is partial (lanes>=48 idle)
            int s = (j >= 16) + (j >= 48) + (j >= 112);
            int C    = 64 << s;
            int toff = (s == 0) ? 0 : (s == 1) ? 200704 : (s == 2) ? 301056 : 351232;
            int jb   = (s == 0) ? 0 : (s == 1) ? 16     : (s == 2) ? 48     : 112;
            int cb   = (j - jb) * 4;

            int id = r[s];
            f32x4 v = (f32x4)(0.0f);
            if (id >= 0) {
                v = *(const f32x4*)(ft + toff + id * C + cb);  // coalesced, L2-hot
            }
            __builtin_nontemporal_store(v, (f32x4*)(rowout + j * 4));
        }
    }
}

extern "C" void kernel_launch(void* const* d_in, const int* in_sizes, int n_in,
                              void* d_out, int out_size, void* d_ws, size_t ws_size,
                              hipStream_t stream) {
    const float* f0  = (const float*)d_in[0];
    const float* f1  = (const float*)d_in[1];
    const float* f2  = (const float*)d_in[2];
    const float* f3  = (const float*)d_in[3];
    const float* pts = (const float*)d_in[4];
    const int* batch = (const int*)d_in[5];

    // ws layout: [ f32 ft[FT_TOTAL] : 1.44 MiB ]
    float* ft = (float*)d_ws;
    float* out = (float*)d_out;

    k_transpose<<<(FT_TOTAL + 255) / 256, 256, 0, stream>>>(f0, f1, f2, f3, batch, ft);
    // 4 points per 256-thread block -> 32768 blocks
    k_gather<<<NPTS / 4, 256, 0, stream>>>(pts, ft, out);
}